// Round 1
// baseline (599.632 us; speedup 1.0000x reference)
//
#include <hip/hip_runtime.h>
#include <math.h>

// Problem constants (from reference): B=16384, N=64, D=64
#define BATCH 16384
#define NN 64
#define DD 64
#define REL_STRIDE 68   // 64 + 4 pad: float4-aligned writes, 8-way read conflict (hidden)

__global__ __launch_bounds__(64)
void aggregator_kernel(const float* __restrict__ self_v,   // [B,1,64]
                       const float* __restrict__ nv,       // [B,1,64,64]
                       const float* __restrict__ rel,      // [B,1,64,64]
                       const float* __restrict__ ue,       // [B,64]
                       const float* __restrict__ W1,       // [128,64]
                       const float* __restrict__ b1,       // [64]
                       const float* __restrict__ w2,       // [64,1]
                       const float* __restrict__ b2,       // [1]
                       float* __restrict__ out)            // [B,1,128]
{
    const int b = blockIdx.x;
    const int t = threadIdx.x;   // 0..63, one wave per block

    __shared__ float rel_s[NN * REL_STRIDE];  // 17408 B
    __shared__ float ue_s[DD];
    __shared__ float u1_s[DD];
    __shared__ float w2_s[DD];
    __shared__ float wbuf[NN];

    const float* relb = rel + (size_t)b * (NN * DD);

    // ---- stage rel (16 KB) into LDS, coalesced float4 loads ----
    #pragma unroll
    for (int i = 0; i < 16; ++i) {
        int f = i * 256 + t * 4;          // lane-contiguous 16B chunks: fully coalesced
        float4 v = *(const float4*)(relb + f);
        int n = f >> 6;                   // row (neighbor)
        int k = f & 63;                   // col
        *(float4*)(&rel_s[n * REL_STRIDE + k]) = v;   // 16B aligned (68%4==0, k%4==0)
    }
    ue_s[t] = ue[(size_t)b * DD + t];
    w2_s[t] = w2[t];
    __syncthreads();

    // ---- u1[j] = b1[j] + sum_k ue[k]*W1[k][j]  (thread j computes one j) ----
    {
        float acc = b1[t];
        #pragma unroll 8
        for (int k = 0; k < DD; ++k) {
            acc = fmaf(ue_s[k], W1[k * DD + t], acc);  // ue_s broadcast; W1 coalesced
        }
        u1_s[t] = acc;
    }
    __syncthreads();

    // ---- hidden for neighbor n = t:  h[j] = u1[j] + sum_k rel[n][k]*W1b[k][j] ----
    float h[DD];
    #pragma unroll
    for (int j = 0; j < DD; ++j) h[j] = u1_s[j];       // uniform addr -> LDS broadcast

    const float* __restrict__ W1b = W1 + DD * DD;      // rows 64..127
    for (int k = 0; k < DD; ++k) {
        float x = rel_s[t * REL_STRIDE + k];           // 8-way bank conflict, hidden
        const float* __restrict__ row = W1b + k * DD;  // wave-uniform -> s_load
        #pragma unroll
        for (int j = 0; j < DD; ++j) h[j] = fmaf(x, row[j], h[j]);
    }

    // ---- decay scalar: sigmoid(relu(h) . w2 + b2) ----
    float d = b2[0];
    #pragma unroll
    for (int j = 0; j < DD; ++j) d = fmaf(fmaxf(h[j], 0.0f), w2_s[j], d);
    float dec = 1.0f / (1.0f + __expf(-d));

    // ---- softmax over the 64 neighbors (one per lane) ----
    float m = dec;
    #pragma unroll
    for (int off = 32; off > 0; off >>= 1) m = fmaxf(m, __shfl_xor(m, off, 64));
    float e = __expf(dec - m);
    float s = e;
    #pragma unroll
    for (int off = 32; off > 0; off >>= 1) s += __shfl_xor(s, off, 64);
    wbuf[t] = e / s;
    __syncthreads();

    // ---- agg[j] = sum_n w[n] * nv[b][n][j]  (thread j; nv reads coalesced) ----
    const float* __restrict__ nvb = nv + (size_t)b * (NN * DD);
    float agg = 0.0f;
    #pragma unroll 8
    for (int n = 0; n < NN; ++n) {
        agg = fmaf(wbuf[n], nvb[n * DD + t], agg);     // wbuf broadcast; nv coalesced
    }

    // ---- output: [self | agg] ----
    out[(size_t)b * (2 * DD) + t]      = self_v[(size_t)b * DD + t];
    out[(size_t)b * (2 * DD) + DD + t] = agg;
}

extern "C" void kernel_launch(void* const* d_in, const int* in_sizes, int n_in,
                              void* d_out, int out_size, void* d_ws, size_t ws_size,
                              hipStream_t stream) {
    const float* self_v = (const float*)d_in[0];
    const float* nv     = (const float*)d_in[1];
    const float* rel    = (const float*)d_in[2];
    const float* ue     = (const float*)d_in[3];
    const float* W1     = (const float*)d_in[4];
    const float* b1     = (const float*)d_in[5];
    const float* w2     = (const float*)d_in[6];
    const float* b2     = (const float*)d_in[7];
    float* out = (float*)d_out;

    aggregator_kernel<<<dim3(BATCH), dim3(64), 0, stream>>>(
        self_v, nv, rel, ue, W1, b1, w2, b2, out);
}